// Round 7
// baseline (704.243 us; speedup 1.0000x reference)
//
#include <hip/hip_runtime.h>
#include <math.h>

// Normalization_60095182406123
//
// Separable 4D Gaussian filter of x^2 over axes (freq, orient, y, x):
//   out[c,y,x] = sum g3[df] g3[do] g32[dy] g32[dx] * xsq[c+(df-1)*16+(do-1)*2, y+dy-16, x+dx-16]
// c = img*192 + freq*16 + orient*2 + phase (same flat layout in and out).
//
// Pass 1 (software-pipelined over 4 y-rows per block, 1 barrier/row):
//   per row: fused x^2 + orient(3) + freq(3) in registers -> LDS (32 rows x 256),
//   then 32-tap x-blur (16 outs/thread) -> ws.  Loads for row y+1 are issued
//   BEFORE the x-blur of row y (double-buffered LDS), hiding HBM latency.
//   __launch_bounds__(512,4): VGPR cap 128 — R6's (512,8) cap of 64 caused
//   massive scratch spills (WRITE_SIZE 150->390 MB).
// Pass 2: blur_y(32) -> out[c,y,x]  (at its memory roofline, unchanged)
//
// ws needs 768*224*224*4 = 154,140,672 bytes of d_ws.

#define SZW   224
#define PLANE (224*224)
#define PW    256          // floats per LDS row: 16 zero | 224 data | 15 zero | 1 spare
#define YB    4            // y rows per block

struct GaussArgs {
    float wx[32];   // 32-tap Gaussian (l=32, w=1), matches reference _gauss
    float w30;      // 3-tap edge   = c*exp(-0.5)
    float w31;      // 3-tap center = c
};

// float4-group swizzle: XOR high group bits and row bits into the bank-quad bits
__device__ __forceinline__ int grp(int row, int g) {
    return (g ^ ((g >> 3) & 7)) ^ (row & 7);
}

__global__ __launch_bounds__(512, 4) void pass1_kernel(const float* __restrict__ in,
                                                       float* __restrict__ ws,
                                                       const GaussArgs ga)
{
    __shared__ float sA[32 * PW];   // 32 KB
    __shared__ float sB[32 * PW];   // 32 KB

    const int tid   = threadIdx.x;
    const int y0    = blockIdx.x * YB;     // 0,4,...,220
    const int by    = blockIdx.y;          // 0..5
    const int phase = by & 1;
    const int fg    = by >> 1;             // 0..2: output f in [4fg, 4fg+4)
    const int img   = blockIdx.z;          // 0..3

    const float w31 = ga.w31;
    const float w30 = ga.w30;

    // ---- per-thread conv geometry (y-independent) ----
    const int xp4 = tid & 63;          // x float4-group
    const int oh  = (tid >> 6) & 1;    // orient half: outputs oh*4 .. oh*4+3
    const int fo  = tid >> 7;          // 0..3
    const int f   = fg*4 + fo;         // output freq
    const bool xok = (xp4 >= 4 && xp4 < 60);
    const int x0  = xp4*4 - 16;

    // 3 freq panels (clamped index, zero weight when out of range)
    const float* pan[3];
    float wjj[3];
    #pragma unroll
    for (int dj = 0; dj < 3; ++dj) {
        int j = f + dj - 1;
        const bool v = (j >= 0 && j < 12);
        wjj[dj] = v ? ((dj == 1) ? w31 : w30) : 0.f;
        j = v ? j : (j < 0 ? 0 : 11);
        pan[dj] = in + (size_t)(img*192 + j*16 + oh*6 + phase)*PLANE + x0;
    }

    // ---- per-thread xblur geometry (y-independent) ----
    const int br   = tid / 14;             // 0..36 (valid rows: tid<448 -> 0..31)
    const int bxg  = tid - br*14;          // 0..13
    const int bch16 = (fg*4 + (br >> 3))*16 + (br & 7)*2;
    const int bxb  = bxg * 16;
    const int browb = br * PW;
    const int bg0  = 4*bxg;

    float4 L[15];

    auto issue = [&](int y) {
        if (xok) {
            #pragma unroll
            for (int dj = 0; dj < 3; ++dj)
                #pragma unroll
                for (int i = 0; i < 5; ++i)
                    L[dj*5+i] = *reinterpret_cast<const float4*>(
                        pan[dj] + (size_t)y*SZW + (size_t)(i*2)*PLANE);
        }
    };

    auto convStore = [&](float* buf) {
        float4 acc[4];
        #pragma unroll
        for (int k = 0; k < 4; ++k) acc[k] = make_float4(0.f,0.f,0.f,0.f);
        #pragma unroll
        for (int dj = 0; dj < 3; ++dj) {
            const float wj = wjj[dj];
            float4 s[5];
            #pragma unroll
            for (int i = 0; i < 5; ++i) {
                float4 v = xok ? L[dj*5+i] : make_float4(0.f,0.f,0.f,0.f);
                s[i] = make_float4(v.x*v.x, v.y*v.y, v.z*v.z, v.w*v.w);
            }
            #pragma unroll
            for (int k = 0; k < 4; ++k) {
                float4 c, l, r;
                if (oh) { c = s[k+1]; l = s[k];
                          r = (k < 3) ? s[k+2] : make_float4(0.f,0.f,0.f,0.f); }
                else    { c = s[k];
                          l = (k > 0) ? s[k-1] : make_float4(0.f,0.f,0.f,0.f);
                          r = s[k+1]; }
                acc[k].x = fmaf(wj, fmaf(w31, c.x, w30*(l.x + r.x)), acc[k].x);
                acc[k].y = fmaf(wj, fmaf(w31, c.y, w30*(l.y + r.y)), acc[k].y);
                acc[k].z = fmaf(wj, fmaf(w31, c.z, w30*(l.z + r.z)), acc[k].z);
                acc[k].w = fmaf(wj, fmaf(w31, c.w, w30*(l.w + r.w)), acc[k].w);
            }
        }
        #pragma unroll
        for (int k = 0; k < 4; ++k) {
            const int row = fo*8 + oh*4 + k;
            *reinterpret_cast<float4*>(&buf[row*PW + grp(row, xp4)*4]) = acc[k];
        }
    };

    auto xblur = [&](const float* buf, int y) {
        if (tid < 448) {
            float acc[16];
            #pragma unroll
            for (int j = 0; j < 16; ++j) acc[j] = 0.f;
            #pragma unroll
            for (int t = 0; t < 12; ++t) {
                const float4 q = *reinterpret_cast<const float4*>(
                    &buf[browb + grp(br, bg0 + t)*4]);
                #pragma unroll
                for (int e = 0; e < 4; ++e) {
                    const int m = 4*t + e;     // window float index 0..47
                    const float qv = (e==0)?q.x:(e==1)?q.y:(e==2)?q.z:q.w;
                    const int jlo = (m - 31 > 0) ? (m - 31) : 0;
                    const int jhi = (m < 15) ? m : 15;
                    #pragma unroll
                    for (int j = jlo; j <= jhi; ++j)
                        acc[j] = fmaf(ga.wx[m - j], qv, acc[j]);
                }
            }
            float* op = ws + (size_t)(img*192 + bch16 + phase)*PLANE
                           + (size_t)y*SZW + bxb;
            #pragma unroll
            for (int s = 0; s < 4; ++s)
                *reinterpret_cast<float4*>(op + 4*s) =
                    make_float4(acc[4*s], acc[4*s+1], acc[4*s+2], acc[4*s+3]);
        }
    };

    // ---- pipelined schedule: loads for y+1 in flight during xblur of y ----
    issue(y0 + 0);
    convStore(sA);
    issue(y0 + 1);
    __syncthreads();

    xblur(sA, y0 + 0);
    convStore(sB);
    issue(y0 + 2);
    __syncthreads();

    xblur(sB, y0 + 1);
    convStore(sA);
    issue(y0 + 3);
    __syncthreads();

    xblur(sA, y0 + 2);
    convStore(sB);
    __syncthreads();

    xblur(sB, y0 + 3);
}

__global__ __launch_bounds__(256) void pass2_kernel(const float* __restrict__ ws,
                                                    float* __restrict__ out,
                                                    const GaussArgs ga)
{
    const int c = blockIdx.x;     // 0..767
    const int x = threadIdx.x;    // column
    if (x >= SZW) return;

    const float* col = ws  + (size_t)c * PLANE + x;
    float*       oc  = out + (size_t)c * PLANE + x;

    float w[47];
    #pragma unroll
    for (int i = 0; i < 47; ++i) {
        int yy = i - 16;
        w[i] = (yy >= 0 && yy < SZW) ? col[yy*SZW] : 0.f;
    }

    #pragma unroll 1
    for (int y0 = 0; y0 < SZW; y0 += 16) {
        float acc[16];
        #pragma unroll
        for (int j = 0; j < 16; ++j) acc[j] = 0.f;
        #pragma unroll
        for (int k = 0; k < 32; ++k) {
            #pragma unroll
            for (int j = 0; j < 16; ++j)
                acc[j] = fmaf(ga.wx[k], w[j+k], acc[j]);
        }
        #pragma unroll
        for (int j = 0; j < 16; ++j) oc[(y0+j)*SZW] = acc[j];

        #pragma unroll
        for (int i = 0; i < 31; ++i) w[i] = w[i+16];
        #pragma unroll
        for (int i = 0; i < 16; ++i) {
            int yy = y0 + 31 + i;
            w[31+i] = (yy < SZW) ? col[yy*SZW] : 0.f;
        }
    }
}

extern "C" void kernel_launch(void* const* d_in, const int* in_sizes, int n_in,
                              void* d_out, int out_size, void* d_ws, size_t ws_size,
                              hipStream_t stream)
{
    const float* x  = (const float*)d_in[0];
    float*      out = (float*)d_out;
    float*      ws  = (float*)d_ws;   // 768*224*224*4 = 154,140,672 B

    // Host-computed Gaussian weights (double precision then rounded to f32 —
    // matches reference _gauss float64 path).
    GaussArgs ga;
    const double c0 = 1.0 / sqrt(2.0 * 3.14159265358979323846);
    for (int k = 0; k < 32; ++k) {
        double t = -1.0 + 2.0 * (double)k / 31.0;
        ga.wx[k] = (float)(c0 * exp(-t * t / 2.0));
    }
    ga.w31 = (float)c0;
    ga.w30 = (float)(c0 * exp(-0.5));

    dim3 g1(SZW / YB, 6, 4);          // (y-tile, phase*freqgroup, img)
    pass1_kernel<<<g1, 512, 0, stream>>>(x, ws, ga);
    pass2_kernel<<<768, 256, 0, stream>>>(ws, out, ga);
}

// Round 8
// 145.119 us; speedup vs baseline: 4.8528x; 4.8528x over previous
//
#include <hip/hip_runtime.h>
#include <hip/hip_fp16.h>
#include <math.h>

// Normalization_60095182406123
//
// Separable 4D Gaussian filter of x^2 over axes (freq, orient, y, x):
//   out[c,y,x] = sum g3[df] g3[do] g32[dy] g32[dx] * xsq[c+(df-1)*16+(do-1)*2, y+dy-16, x+dx-16]
// c = img*192 + freq*16 + orient*2 + phase (same flat layout in and out).
//
// R8 = R5 structure (proven 104+51 µs) with ws in FP16 (halves the 300 MB
// ws round-trip; fp16 rel-err 5e-4 adds <0.15 absmax vs 1.97 threshold).
//
// Pass 1: x^2 + orient(3) + freq(3) + blur_x(32) -> ws[c,y,x] (fp16)
//   - freq split 3-way (4 output freqs + 1 halo each side = 6 staged)
//   - LDS 48 rows x 256 floats = 49,152 B -> 3 blocks/CU
//   - step 3: 16 outputs/thread (12 ds_read_b128 per 16 outs)
//   - XOR group swizzle g^=(g>>3)&7 breaks the stride-64B bank pattern
//   - weights host-computed, passed as kernel args
// Pass 2: blur_y(32), fp16 ws -> fp32 out
//
// ws needs 768*224*224*2 = 77,070,336 bytes of d_ws.

#define SZW   224
#define PLANE (224*224)
#define PW    256          // floats per LDS row: 16 zero | 224 data | 15 zero | 1 spare

struct GaussArgs {
    float wx[32];   // 32-tap Gaussian (l=32, w=1), matches reference _gauss
    float w30;      // 3-tap edge   = c*exp(-0.5)
    float w31;      // 3-tap center = c
};

// within-row float4-group swizzle (involution, preserves 8-group blocks)
__device__ __forceinline__ int swz(int g) { return g ^ ((g >> 3) & 7); }

__global__ __launch_bounds__(512, 6) void pass1_kernel(const float* __restrict__ in,
                                                       __half* __restrict__ ws,
                                                       const GaussArgs ga)
{
    __shared__ float s2[48 * PW];   // 49,152 B

    const int tid   = threadIdx.x;
    const int y     = blockIdx.x;          // 0..223
    const int by    = blockIdx.y;          // 0..5
    const int phase = by & 1;
    const int fg    = by >> 1;             // freq group: output f in [4fg, 4fg+4)
    const int img   = blockIdx.z;          // 0..3

    const float w31 = ga.w31;
    const float w30 = ga.w30;

    // ---- step 1: load x^2 (x-padded), orient 3-tap conv in regs, to LDS ----
    // 6 staged freqs lf=0..5 -> f = 4fg-1+lf; 64 float4 groups per row.
    if (tid < 384) {
        const int lf  = tid >> 6;          // 0..5
        const int xp4 = tid & 63;
        const int f   = 4*fg - 1 + lf;     // -1..12
        const int gsw = swz(xp4);
        float4 a[8];
        if (f >= 0 && f < 12 && xp4 >= 4 && xp4 < 60) {
            const int x0 = xp4*4 - 16;     // 0..220, 16B-aligned
            const float* base = in + (size_t)(img*192 + f*16 + phase)*PLANE + y*SZW + x0;
            #pragma unroll
            for (int o = 0; o < 8; ++o) {
                float4 v = *reinterpret_cast<const float4*>(base + o*2*PLANE);
                a[o] = make_float4(v.x*v.x, v.y*v.y, v.z*v.z, v.w*v.w);
            }
        } else {
            #pragma unroll
            for (int o = 0; o < 8; ++o) a[o] = make_float4(0.f,0.f,0.f,0.f);
        }
        #pragma unroll
        for (int o = 0; o < 8; ++o) {
            float4 l = (o > 0) ? a[o-1] : make_float4(0.f,0.f,0.f,0.f);
            float4 r = (o < 7) ? a[o+1] : make_float4(0.f,0.f,0.f,0.f);
            float4 b;
            b.x = fmaf(w31, a[o].x, w30*(l.x + r.x));
            b.y = fmaf(w31, a[o].y, w30*(l.y + r.y));
            b.z = fmaf(w31, a[o].z, w30*(l.z + r.z));
            b.w = fmaf(w31, a[o].w, w30*(l.w + r.w));
            *reinterpret_cast<float4*>(&s2[(lf*8 + o)*PW + gsw*4]) = b;
        }
    }
    __syncthreads();

    // ---- step 2: freq 3-tap conv in place (thread owns its (o, xp4) column) ----
    {
        const int o   = tid >> 6;          // 0..7
        const int xp4 = tid & 63;
        const int gsw = swz(xp4);
        float4 a[6];
        #pragma unroll
        for (int lf = 0; lf < 6; ++lf)
            a[lf] = *reinterpret_cast<const float4*>(&s2[(lf*8 + o)*PW + gsw*4]);
        #pragma unroll
        for (int lf = 1; lf < 5; ++lf) {
            float4 b;
            b.x = fmaf(w31, a[lf].x, w30*(a[lf-1].x + a[lf+1].x));
            b.y = fmaf(w31, a[lf].y, w30*(a[lf-1].y + a[lf+1].y));
            b.z = fmaf(w31, a[lf].z, w30*(a[lf-1].z + a[lf+1].z));
            b.w = fmaf(w31, a[lf].w, w30*(a[lf-1].w + a[lf+1].w));
            *reinterpret_cast<float4*>(&s2[(lf*8 + o)*PW + gsw*4]) = b;
        }
    }
    __syncthreads();

    // ---- step 3: 32-tap blur along x, 16 outputs/thread, fp16 store ----
    // 32 output rows (lf 1..4, o 0..7) x 14 groups-of-16 = 448 units = 7 waves.
    if (tid < 448) {
        const int r  = tid / 14;           // 0..31
        const int xg = tid - r*14;         // 0..13
        const int lf = 1 + (r >> 3);
        const int o  = r & 7;
        const int fo16 = (4*fg + (r >> 3))*16 + o*2;
        const int x0 = xg * 16;            // output x base (0..208)
        const int rowb = (lf*8 + o)*PW;
        const int g0 = 4*xg;

        float acc[16];
        #pragma unroll
        for (int j = 0; j < 16; ++j) acc[j] = 0.f;

        #pragma unroll
        for (int t = 0; t < 12; ++t) {
            const float4 q = *reinterpret_cast<const float4*>(
                &s2[rowb + swz(g0 + t)*4]);
            #pragma unroll
            for (int e = 0; e < 4; ++e) {
                const int m = 4*t + e;     // window float index 0..47
                const float qv = (e==0)?q.x:(e==1)?q.y:(e==2)?q.z:q.w;
                const int jlo = (m - 31 > 0) ? (m - 31) : 0;
                const int jhi = (m < 15) ? m : 15;
                #pragma unroll
                for (int j = jlo; j <= jhi; ++j)
                    acc[j] = fmaf(ga.wx[m - j], qv, acc[j]);
            }
        }

        // pack 16 floats -> 8 half2 -> two 16B stores
        union { uint4 u4[2]; __half2 h2[8]; } pk;
        #pragma unroll
        for (int s = 0; s < 8; ++s)
            pk.h2[s] = __floats2half2_rn(acc[2*s], acc[2*s+1]);

        __half* op = ws + (size_t)(img*192 + phase)*PLANE + (size_t)y*SZW
                        + (size_t)fo16*PLANE + x0;
        *reinterpret_cast<uint4*>(op)     = pk.u4[0];
        *reinterpret_cast<uint4*>(op + 8) = pk.u4[1];
    }
}

__global__ __launch_bounds__(256) void pass2_kernel(const __half* __restrict__ ws,
                                                    float* __restrict__ out,
                                                    const GaussArgs ga)
{
    const int c = blockIdx.x;     // 0..767
    const int x = threadIdx.x;    // column
    if (x >= SZW) return;

    const __half* col = ws  + (size_t)c * PLANE + x;
    float*        oc  = out + (size_t)c * PLANE + x;

    float w[47];
    #pragma unroll
    for (int i = 0; i < 47; ++i) {
        int yy = i - 16;
        w[i] = (yy >= 0 && yy < SZW) ? __half2float(col[(size_t)yy*SZW]) : 0.f;
    }

    #pragma unroll 1
    for (int y0 = 0; y0 < SZW; y0 += 16) {
        float acc[16];
        #pragma unroll
        for (int j = 0; j < 16; ++j) acc[j] = 0.f;
        #pragma unroll
        for (int k = 0; k < 32; ++k) {
            #pragma unroll
            for (int j = 0; j < 16; ++j)
                acc[j] = fmaf(ga.wx[k], w[j+k], acc[j]);
        }
        #pragma unroll
        for (int j = 0; j < 16; ++j) oc[(size_t)(y0+j)*SZW] = acc[j];

        #pragma unroll
        for (int i = 0; i < 31; ++i) w[i] = w[i+16];
        #pragma unroll
        for (int i = 0; i < 16; ++i) {
            int yy = y0 + 31 + i;
            w[31+i] = (yy < SZW) ? __half2float(col[(size_t)yy*SZW]) : 0.f;
        }
    }
}

extern "C" void kernel_launch(void* const* d_in, const int* in_sizes, int n_in,
                              void* d_out, int out_size, void* d_ws, size_t ws_size,
                              hipStream_t stream)
{
    const float* x  = (const float*)d_in[0];
    float*      out = (float*)d_out;
    __half*     ws  = (__half*)d_ws;  // 768*224*224*2 = 77,070,336 B

    // Host-computed Gaussian weights (double precision then rounded to f32 —
    // matches reference _gauss float64 path).
    GaussArgs ga;
    const double c0 = 1.0 / sqrt(2.0 * 3.14159265358979323846);
    for (int k = 0; k < 32; ++k) {
        double t = -1.0 + 2.0 * (double)k / 31.0;
        ga.wx[k] = (float)(c0 * exp(-t * t / 2.0));
    }
    ga.w31 = (float)c0;
    ga.w30 = (float)(c0 * exp(-0.5));

    dim3 g1(SZW, 6, 4);               // (y, phase*freqgroup, img)
    pass1_kernel<<<g1, 512, 0, stream>>>(x, ws, ga);
    pass2_kernel<<<768, 256, 0, stream>>>(ws, out, ga);
}

// Round 9
// 136.935 us; speedup vs baseline: 5.1429x; 1.0598x over previous
//
#include <hip/hip_runtime.h>
#include <hip/hip_fp16.h>
#include <math.h>

// Normalization_60095182406123
//
// Separable 4D Gaussian filter of x^2 over axes (freq, orient, y, x):
//   out[c,y,x] = sum g3[df] g3[do] g32[dy] g32[dx] * xsq[c+(df-1)*16+(do-1)*2, y+dy-16, x+dx-16]
// c = img*192 + freq*16 + orient*2 + phase (same flat layout in and out).
//
// Pass 1 (R8, unchanged): x^2 + orient(3) + freq(3) + blur_x(32) -> ws (fp16), ~38 us
// Pass 2 (R9): blur_y(32) fp16->fp32, y-split x4 (3072 blocks) + 8-output tiles
//   with prefetched window loads (R8 was latency-bound at 26% occupancy).
//
// ws needs 768*224*224*2 = 77,070,336 bytes of d_ws.

#define SZW   224
#define PLANE (224*224)
#define PW    256          // floats per LDS row: 16 zero | 224 data | 15 zero | 1 spare

struct GaussArgs {
    float wx[32];   // 32-tap Gaussian (l=32, w=1), matches reference _gauss
    float w30;      // 3-tap edge   = c*exp(-0.5)
    float w31;      // 3-tap center = c
};

// within-row float4-group swizzle (involution, preserves 8-group blocks)
__device__ __forceinline__ int swz(int g) { return g ^ ((g >> 3) & 7); }

__global__ __launch_bounds__(512, 6) void pass1_kernel(const float* __restrict__ in,
                                                       __half* __restrict__ ws,
                                                       const GaussArgs ga)
{
    __shared__ float s2[48 * PW];   // 49,152 B

    const int tid   = threadIdx.x;
    const int y     = blockIdx.x;          // 0..223
    const int by    = blockIdx.y;          // 0..5
    const int phase = by & 1;
    const int fg    = by >> 1;             // freq group: output f in [4fg, 4fg+4)
    const int img   = blockIdx.z;          // 0..3

    const float w31 = ga.w31;
    const float w30 = ga.w30;

    // ---- step 1: load x^2 (x-padded), orient 3-tap conv in regs, to LDS ----
    if (tid < 384) {
        const int lf  = tid >> 6;          // 0..5
        const int xp4 = tid & 63;
        const int f   = 4*fg - 1 + lf;     // -1..12
        const int gsw = swz(xp4);
        float4 a[8];
        if (f >= 0 && f < 12 && xp4 >= 4 && xp4 < 60) {
            const int x0 = xp4*4 - 16;     // 0..220, 16B-aligned
            const float* base = in + (size_t)(img*192 + f*16 + phase)*PLANE + y*SZW + x0;
            #pragma unroll
            for (int o = 0; o < 8; ++o) {
                float4 v = *reinterpret_cast<const float4*>(base + o*2*PLANE);
                a[o] = make_float4(v.x*v.x, v.y*v.y, v.z*v.z, v.w*v.w);
            }
        } else {
            #pragma unroll
            for (int o = 0; o < 8; ++o) a[o] = make_float4(0.f,0.f,0.f,0.f);
        }
        #pragma unroll
        for (int o = 0; o < 8; ++o) {
            float4 l = (o > 0) ? a[o-1] : make_float4(0.f,0.f,0.f,0.f);
            float4 r = (o < 7) ? a[o+1] : make_float4(0.f,0.f,0.f,0.f);
            float4 b;
            b.x = fmaf(w31, a[o].x, w30*(l.x + r.x));
            b.y = fmaf(w31, a[o].y, w30*(l.y + r.y));
            b.z = fmaf(w31, a[o].z, w30*(l.z + r.z));
            b.w = fmaf(w31, a[o].w, w30*(l.w + r.w));
            *reinterpret_cast<float4*>(&s2[(lf*8 + o)*PW + gsw*4]) = b;
        }
    }
    __syncthreads();

    // ---- step 2: freq 3-tap conv in place ----
    {
        const int o   = tid >> 6;          // 0..7
        const int xp4 = tid & 63;
        const int gsw = swz(xp4);
        float4 a[6];
        #pragma unroll
        for (int lf = 0; lf < 6; ++lf)
            a[lf] = *reinterpret_cast<const float4*>(&s2[(lf*8 + o)*PW + gsw*4]);
        #pragma unroll
        for (int lf = 1; lf < 5; ++lf) {
            float4 b;
            b.x = fmaf(w31, a[lf].x, w30*(a[lf-1].x + a[lf+1].x));
            b.y = fmaf(w31, a[lf].y, w30*(a[lf-1].y + a[lf+1].y));
            b.z = fmaf(w31, a[lf].z, w30*(a[lf-1].z + a[lf+1].z));
            b.w = fmaf(w31, a[lf].w, w30*(a[lf-1].w + a[lf+1].w));
            *reinterpret_cast<float4*>(&s2[(lf*8 + o)*PW + gsw*4]) = b;
        }
    }
    __syncthreads();

    // ---- step 3: 32-tap blur along x, 16 outputs/thread, fp16 store ----
    if (tid < 448) {
        const int r  = tid / 14;           // 0..31
        const int xg = tid - r*14;         // 0..13
        const int lf = 1 + (r >> 3);
        const int o  = r & 7;
        const int fo16 = (4*fg + (r >> 3))*16 + o*2;
        const int x0 = xg * 16;            // output x base (0..208)
        const int rowb = (lf*8 + o)*PW;
        const int g0 = 4*xg;

        float acc[16];
        #pragma unroll
        for (int j = 0; j < 16; ++j) acc[j] = 0.f;

        #pragma unroll
        for (int t = 0; t < 12; ++t) {
            const float4 q = *reinterpret_cast<const float4*>(
                &s2[rowb + swz(g0 + t)*4]);
            #pragma unroll
            for (int e = 0; e < 4; ++e) {
                const int m = 4*t + e;     // window float index 0..47
                const float qv = (e==0)?q.x:(e==1)?q.y:(e==2)?q.z:q.w;
                const int jlo = (m - 31 > 0) ? (m - 31) : 0;
                const int jhi = (m < 15) ? m : 15;
                #pragma unroll
                for (int j = jlo; j <= jhi; ++j)
                    acc[j] = fmaf(ga.wx[m - j], qv, acc[j]);
            }
        }

        union { uint4 u4[2]; __half2 h2[8]; } pk;
        #pragma unroll
        for (int s = 0; s < 8; ++s)
            pk.h2[s] = __floats2half2_rn(acc[2*s], acc[2*s+1]);

        __half* op = ws + (size_t)(img*192 + phase)*PLANE + (size_t)y*SZW
                        + (size_t)fo16*PLANE + x0;
        *reinterpret_cast<uint4*>(op)     = pk.u4[0];
        *reinterpret_cast<uint4*>(op + 8) = pk.u4[1];
    }
}

// Pass 2: y-blur. Grid (c=768, yt=4); each block computes 56 output rows of one
// channel. 8-output tiles, 39-float rolling window, prefetched loads.
__global__ __launch_bounds__(256) void pass2_kernel(const __half* __restrict__ ws,
                                                    float* __restrict__ out,
                                                    const GaussArgs ga)
{
    const int c  = blockIdx.x;    // 0..767
    const int yt = blockIdx.y;    // 0..3
    const int x  = threadIdx.x;   // column
    if (x >= SZW) return;

    const int yb = yt * 56;       // output tile base

    const __half* col = ws  + (size_t)c * PLANE + x;
    float*        oc  = out + (size_t)c * PLANE + x;

    // window w[i] = row(yb - 16 + i), i = 0..38
    float w[39];
    #pragma unroll
    for (int i = 0; i < 39; ++i) {
        int yy = yb - 16 + i;
        w[i] = (yy >= 0 && yy < SZW) ? __half2float(col[(size_t)yy * SZW]) : 0.f;
    }

    #pragma unroll 1
    for (int t = 0; t < 7; ++t) {
        const int y0 = yb + t*8;

        // prefetch the next 8 window rows (y0+23 .. y0+30)
        float nf[8];
        #pragma unroll
        for (int i = 0; i < 8; ++i) {
            int yy = y0 + 23 + i;
            nf[i] = (yy < SZW) ? __half2float(col[(size_t)yy * SZW]) : 0.f;
        }

        float acc[8];
        #pragma unroll
        for (int j = 0; j < 8; ++j) acc[j] = 0.f;
        #pragma unroll
        for (int k = 0; k < 32; ++k) {
            #pragma unroll
            for (int j = 0; j < 8; ++j)
                acc[j] = fmaf(ga.wx[k], w[j+k], acc[j]);
        }
        #pragma unroll
        for (int j = 0; j < 8; ++j) oc[(size_t)(y0+j) * SZW] = acc[j];

        // shift window by 8, append prefetched rows
        #pragma unroll
        for (int i = 0; i < 31; ++i) w[i] = w[i+8];
        #pragma unroll
        for (int i = 0; i < 8; ++i) w[31+i] = nf[i];
    }
}

extern "C" void kernel_launch(void* const* d_in, const int* in_sizes, int n_in,
                              void* d_out, int out_size, void* d_ws, size_t ws_size,
                              hipStream_t stream)
{
    const float* x  = (const float*)d_in[0];
    float*      out = (float*)d_out;
    __half*     ws  = (__half*)d_ws;  // 768*224*224*2 = 77,070,336 B

    // Host-computed Gaussian weights (double precision then rounded to f32 —
    // matches reference _gauss float64 path).
    GaussArgs ga;
    const double c0 = 1.0 / sqrt(2.0 * 3.14159265358979323846);
    for (int k = 0; k < 32; ++k) {
        double t = -1.0 + 2.0 * (double)k / 31.0;
        ga.wx[k] = (float)(c0 * exp(-t * t / 2.0));
    }
    ga.w31 = (float)c0;
    ga.w30 = (float)(c0 * exp(-0.5));

    dim3 g1(SZW, 6, 4);               // (y, phase*freqgroup, img)
    pass1_kernel<<<g1, 512, 0, stream>>>(x, ws, ga);
    dim3 g2(768, 4);                  // (channel, y-tile)
    pass2_kernel<<<g2, 256, 0, stream>>>(ws, out, ga);
}